// Round 5
// baseline (177.484 us; speedup 1.0000x reference)
//
#include <hip/hip_runtime.h>

#define NEG_INF (-9999999.0f)

typedef __attribute__((ext_vector_type(8))) short bf16x8;
typedef __attribute__((ext_vector_type(4))) float f32x4;
typedef unsigned short us;
typedef unsigned int u32;

#define MFMA16 __builtin_amdgcn_mfma_f32_16x16x32_bf16

__device__ __forceinline__ float b2f(us u) {
  union { unsigned int i; float f; } x; x.i = ((unsigned int)u) << 16; return x.f;
}
__device__ __forceinline__ us f2b(float f) {
  union { float f; unsigned int i; } x; x.f = f;
  unsigned int r = x.i + 0x7fffu + ((x.i >> 16) & 1u);
  return (us)(r >> 16);
}
__device__ __forceinline__ float lrelu(float v) { return v > 0.f ? v : 0.01f * v; }
__device__ __forceinline__ bf16x8 ld8(const us* p) { return *reinterpret_cast<const bf16x8*>(p); }
// XOR swizzle for N-row x 320-col bf16 LDS panels (row pitch 640 B).
__device__ __forceinline__ int swz(int row) { return (row & 7) << 4; }

// ---------------- prep0: Ws -> bf16 [320][320] (critical path only) ----------------
__global__ __launch_bounds__(256) void k_prep0(
    const float* __restrict__ Ws, us* __restrict__ Wsb) {
  int gid = blockIdx.x * 256 + threadIdx.x;
  for (int i = gid; i < 320 * 320; i += 128 * 256) {
    int r = i / 320, c = i - r * 320;
    Wsb[i] = (r < 300 && c < 300) ? f2b(Ws[r * 300 + c]) : (us)0;
  }
}

// ------- sweepM: M A-row-tiles from swizzled LDS, B rows from global (depth-2) --
template<int M, int NT, int KS>
__device__ __forceinline__ void sweepM(const us* __restrict__ Alds, const int (&rr)[M],
    int q, int lo, const us* __restrict__ Bg, int n0, f32x4 (&acc)[M][NT]) {
  const char* ab = (const char*)Alds;
  int ao[M], sw[M];
#pragma unroll
  for (int m = 0; m < M; ++m) { ao[m] = rr[m] * 640; sw[m] = swz(rr[m]); }
  const us* br[NT];
#pragma unroll
  for (int t = 0; t < NT; ++t)
    br[t] = Bg + (long)((n0 + t) * 16 + lo) * 320 + 8 * q;
  bf16x8 aC[M], aN[M], b0[NT], b1[NT];
#pragma unroll
  for (int m = 0; m < M; ++m) {
    aC[m] = *(const bf16x8*)(ab + ao[m] + ((16 * q) ^ sw[m]));
    aN[m] = *(const bf16x8*)(ab + ao[m] + ((64 + 16 * q) ^ sw[m]));
  }
#pragma unroll
  for (int t = 0; t < NT; ++t) b0[t] = ld8(br[t]);
#pragma unroll
  for (int t = 0; t < NT; ++t) b1[t] = ld8(br[t] + 32);
#pragma unroll
  for (int ks = 0; ks < KS - 2; ++ks) {
    bf16x8 aF[M], bF[NT];
    const int kb = 64 * (ks + 2) + 16 * q;
#pragma unroll
    for (int m = 0; m < M; ++m) aF[m] = *(const bf16x8*)(ab + ao[m] + (kb ^ sw[m]));
#pragma unroll
    for (int t = 0; t < NT; ++t) bF[t] = ld8(br[t] + (ks + 2) * 32);
#pragma unroll
    for (int t = 0; t < NT; ++t)
#pragma unroll
      for (int m = 0; m < M; ++m)
        acc[m][t] = MFMA16(aC[m], b0[t], acc[m][t], 0, 0, 0);
#pragma unroll
    for (int m = 0; m < M; ++m) { aC[m] = aN[m]; aN[m] = aF[m]; }
#pragma unroll
    for (int t = 0; t < NT; ++t) { b0[t] = b1[t]; b1[t] = bF[t]; }
  }
#pragma unroll
  for (int t = 0; t < NT; ++t)
#pragma unroll
    for (int m = 0; m < M; ++m) acc[m][t] = MFMA16(aC[m], b0[t], acc[m][t], 0, 0, 0);
#pragma unroll
  for (int t = 0; t < NT; ++t)
#pragma unroll
    for (int m = 0; m < M; ++m) acc[m][t] = MFMA16(aN[m], b1[t], acc[m][t], 0, 0, 0);
}

// ------- sweepT: A (output h-rows) from global weight rows, B = NB x 16 enc rows (LDS) ----
template<int NB, int NT, int KS>
__device__ __forceinline__ void sweepT(const us* __restrict__ es, int q, int lo,
    const us* __restrict__ Ag, int n0, f32x4 (&acc)[NB][NT]) {
  const char* eb = (const char*)es;
  int bo[NB], sb[NB];
#pragma unroll
  for (int h = 0; h < NB; ++h) { bo[h] = (lo + 16 * h) * 640; sb[h] = swz(lo + 16 * h); }
  const us* ar[NT];
#pragma unroll
  for (int t = 0; t < NT; ++t)
    ar[t] = Ag + (long)((n0 + t) * 16 + lo) * 320 + 8 * q;
  bf16x8 a0[NT], a1[NT], bC[NB], bN[NB];
#pragma unroll
  for (int t = 0; t < NT; ++t) a0[t] = ld8(ar[t]);
#pragma unroll
  for (int h = 0; h < NB; ++h)
    bC[h] = *(const bf16x8*)(eb + bo[h] + ((16 * q) ^ sb[h]));
#pragma unroll
  for (int t = 0; t < NT; ++t) a1[t] = ld8(ar[t] + 32);
#pragma unroll
  for (int h = 0; h < NB; ++h)
    bN[h] = *(const bf16x8*)(eb + bo[h] + ((64 + 16 * q) ^ sb[h]));
#pragma unroll
  for (int ks = 0; ks < KS - 2; ++ks) {
    bf16x8 a2[NT], bF[NB];
    const int kb = 64 * (ks + 2) + 16 * q;
#pragma unroll
    for (int t = 0; t < NT; ++t) a2[t] = ld8(ar[t] + (ks + 2) * 32);
#pragma unroll
    for (int h = 0; h < NB; ++h)
      bF[h] = *(const bf16x8*)(eb + bo[h] + (kb ^ sb[h]));
#pragma unroll
    for (int t = 0; t < NT; ++t)
#pragma unroll
      for (int h = 0; h < NB; ++h)
        acc[h][t] = MFMA16(a0[t], bC[h], acc[h][t], 0, 0, 0);
#pragma unroll
    for (int t = 0; t < NT; ++t) { a0[t] = a1[t]; a1[t] = a2[t]; }
#pragma unroll
    for (int h = 0; h < NB; ++h) { bC[h] = bN[h]; bN[h] = bF[h]; }
  }
#pragma unroll
  for (int t = 0; t < NT; ++t)
#pragma unroll
    for (int h = 0; h < NB; ++h) acc[h][t] = MFMA16(a0[t], bC[h], acc[h][t], 0, 0, 0);
#pragma unroll
  for (int t = 0; t < NT; ++t)
#pragma unroll
    for (int h = 0; h < NB; ++h) acc[h][t] = MFMA16(a1[t], bN[h], acc[h][t], 0, 0, 0);
}

// ------- sweepG: both operands from global (depth-2) — for k_doc logits ----------
template<int NT>
__device__ __forceinline__ void sweepG(const us* __restrict__ Ab,
    const us* __restrict__ Bb, int m0, int nt0, int lo, int q, int ksn, f32x4* acc) {
  const us* ar = Ab + (long)(m0 + lo) * 320 + 8 * q;
  const us* br[NT];
#pragma unroll
  for (int t = 0; t < NT; ++t)
    br[t] = Bb + (long)((nt0 + t) * 16 + lo) * 320 + 8 * q;
  bf16x8 a0 = ld8(ar), a1 = ld8(ar + 32);
  bf16x8 b0[NT], b1[NT];
#pragma unroll
  for (int t = 0; t < NT; ++t) b0[t] = ld8(br[t]);
#pragma unroll
  for (int t = 0; t < NT; ++t) b1[t] = ld8(br[t] + 32);
  for (int ks = 0; ks < ksn - 2; ++ks) {
    bf16x8 a2 = ld8(ar + (ks + 2) * 32);
    bf16x8 b2[NT];
#pragma unroll
    for (int t = 0; t < NT; ++t) b2[t] = ld8(br[t] + (ks + 2) * 32);
#pragma unroll
    for (int t = 0; t < NT; ++t)
      acc[t] = MFMA16(a0, b0[t], acc[t], 0, 0, 0);
    a0 = a1; a1 = a2;
#pragma unroll
    for (int t = 0; t < NT; ++t) { b0[t] = b1[t]; b1[t] = b2[t]; }
  }
#pragma unroll
  for (int t = 0; t < NT; ++t)
    acc[t] = MFMA16(a0, b0[t], acc[t], 0, 0, 0);
#pragma unroll
  for (int t = 0; t < NT; ++t)
    acc[t] = MFMA16(a1, b1[t], acc[t], 0, 0, 0);
}

// ------- K1: x<128: gather + enc(M=2) + scores; x>=128: convert Wp/Wc/Wr3/c2 ---------
__global__ __launch_bounds__(256) void k_encprep(
    const int* __restrict__ wi, const float* __restrict__ E,
    const us* __restrict__ Wsb, const float* __restrict__ b_sent,
    const float* __restrict__ w_root,
    const float* __restrict__ Wp, const float* __restrict__ Wc,
    const float* __restrict__ Wr, const float* __restrict__ root,
    us* __restrict__ encG, float* __restrict__ scG,
    us* __restrict__ Wpb, us* __restrict__ Wcb, us* __restrict__ Wr3b,
    float* __restrict__ c2) {
  int t = threadIdx.x;
  if (blockIdx.x >= 128) {
    int gid = (blockIdx.x - 128) * 256 + t;
    const int stride = 160 * 256;
    for (int i = gid; i < 5 * 102400; i += stride) {
      int p = i / 102400, rem = i - p * 102400;
      int r = rem / 320, c = rem - r * 320;
      us v = 0;
      if (r < 300 && c < 300) {
        if (p == 0)      v = f2b(Wp[r * 300 + c]);
        else if (p == 1) v = f2b(Wc[r * 300 + c]);
        else             v = f2b(Wr[r * 900 + (p - 2) * 300 + c]);
      }
      if (p == 0)      Wpb[rem] = v;
      else if (p == 1) Wcb[rem] = v;
      else             Wr3b[(p - 2) * 102400 + rem] = v;
    }
    if (gid < 2560) {   // c2[c] = sum_h Wr2[c][h]*root[h]
      int c = gid >> 3, p = gid & 7;
      float s = 0.f;
      if (c < 300)
        for (int h = p; h < 300; h += 8) s = fmaf(Wr[c * 900 + 300 + h], root[h], s);
      s += __shfl_xor(s, 1); s += __shfl_xor(s, 2); s += __shfl_xor(s, 4);
      if (p == 0) c2[c] = s;
    }
    return;
  }
  // ---- enc path: 32-row tile ----
  __shared__ __align__(16) us xs[32 * 320];
  __shared__ __align__(16) us es[32 * 320];
  int r0g = blockIdx.x * 32;
  {
    int row = t >> 3, p = t & 7;
    int widx = wi[((r0g + row) << 6) + 63];
    const float4* er = (const float4*)(E + (long)widx * 300);
    char* rowb = (char*)xs + row * 640;
    int sw = swz(row);
    for (int j = p; j < 75; j += 8) {
      float4 v = er[j];
      *(ushort4*)(rowb + ((8 * j) ^ sw)) =
          make_ushort4(f2b(v.x), f2b(v.y), f2b(v.z), f2b(v.w));
    }
    for (int c = 300 + p; c < 320; c += 8)    // zero K-pad cols
      *(us*)(rowb + ((2 * c) ^ sw)) = 0;
  }
  __syncthreads();
  int w = t >> 6, lane = t & 63, lo = lane & 15, q = lane >> 4;
  const f32x4 z4 = {0.f, 0.f, 0.f, 0.f};
  int rr[2] = { lo, 16 + lo };
  f32x4 acc[2][5];
#pragma unroll
  for (int a = 0; a < 2; ++a)
#pragma unroll
    for (int b = 0; b < 5; ++b) acc[a][b] = z4;
  sweepM<2, 5, 10>(xs, rr, q, lo, Wsb, w * 5, acc);
#pragma unroll
  for (int m = 0; m < 2; ++m)
#pragma unroll
    for (int tt = 0; tt < 5; ++tt) {
      int col = (w * 5 + tt) * 16 + lo;
      float bb = (col < 300) ? b_sent[col] : 0.f;
#pragma unroll
      for (int r = 0; r < 4; ++r) {
        int row = m * 16 + 4 * q + r;
        us hv = (col < 300) ? f2b(lrelu(acc[m][tt][r] + bb)) : (us)0;
        *(us*)((char*)es + row * 640 + ((2 * col) ^ swz(row))) = hv;
        encG[(long)(r0g + row) * 320 + col] = hv;
      }
    }
  __syncthreads();
  // scores = enc @ w_root (b_root omitted: softmax-invariant)
  {
    int row = t >> 3, p = t & 7;
    float s = 0.f;
    for (int cch = p; cch < 38; cch += 8) {
      bf16x8 v = *(const bf16x8*)((const char*)es + row * 640 + ((16 * cch) ^ swz(row)));
#pragma unroll
      for (int e = 0; e < 8; ++e) {
        int h = cch * 8 + e;
        if (h < 300) s = fmaf(b2f((us)v[e]), w_root[h], s);
      }
    }
    s += __shfl_xor(s, 1); s += __shfl_xor(s, 2); s += __shfl_xor(s, 4);
    if (p == 0) scG[r0g + row] = s;
  }
}

// ---------------- K2: 64 row-tiles (64 rows) x 5 tasks {P, C, G1T, G3T, G2eT} -------------
__global__ __launch_bounds__(256) void k_panels(
    const us* __restrict__ encG,
    const us* __restrict__ Wpb, const us* __restrict__ Wcb, const us* __restrict__ Wrb,
    const float* __restrict__ b_par, const float* __restrict__ b_ch,
    us* __restrict__ Pg, us* __restrict__ Cg, us* __restrict__ G1T, us* __restrict__ G3T,
    us* __restrict__ G2eT) {
  __shared__ __align__(16) us es[64 * 320];
  int t = threadIdx.x, task = blockIdx.y, rt = blockIdx.x;
  // stage 64-row enc tile (pad cols already zero in encG), swizzled
  {
    const float4* src = (const float4*)(encG + (long)rt * 64 * 320);
    for (int i = t; i < 2560; i += 256) {
      int row = i / 40, c16 = i - row * 40;
      float4 v = src[i];
      *(float4*)((char*)es + row * 640 + ((c16 * 16) ^ swz(row))) = v;
    }
  }
  __syncthreads();
  int w = t >> 6, lane = t & 63, lo = lane & 15, q = lane >> 4;
  const f32x4 z4 = {0.f, 0.f, 0.f, 0.f};
  if (task < 2) {
    const us* Bg = task ? Wcb : Wpb;
    const float* bias = task ? b_ch : b_par;
    us* outb = task ? Cg : Pg;
    int rr[4] = { lo, 16 + lo, 32 + lo, 48 + lo };
    f32x4 acc[4][5];
#pragma unroll
    for (int a = 0; a < 4; ++a)
#pragma unroll
      for (int b = 0; b < 5; ++b) acc[a][b] = z4;
    sweepM<4, 5, 10>(es, rr, q, lo, Bg, w * 5, acc);
#pragma unroll
    for (int m = 0; m < 4; ++m)
#pragma unroll
      for (int tt = 0; tt < 5; ++tt) {
        int col = (w * 5 + tt) * 16 + lo;
        float bb = (col < 300) ? bias[col] : 0.f;
#pragma unroll
        for (int r = 0; r < 4; ++r) {
          int row = rt * 64 + m * 16 + 4 * q + r;
          outb[(long)row * 320 + col] =
              (col < 300) ? f2b(lrelu(acc[m][tt][r] + bb)) : (us)0;
        }
      }
  } else {
    // transposed outputs [h][row]: G1T / G3T / G2eT
    const us* Ag = (task == 2) ? Wrb : (task == 3) ? Wrb + 204800 : Wrb + 102400;
    us* outb = (task == 2) ? G1T : (task == 3) ? G3T : G2eT;
    f32x4 acc[4][5];
#pragma unroll
    for (int a = 0; a < 4; ++a)
#pragma unroll
      for (int b = 0; b < 5; ++b) acc[a][b] = z4;
    sweepT<4, 5, 10>(es, q, lo, Ag, w * 5, acc);
#pragma unroll
    for (int half = 0; half < 4; ++half)
#pragma unroll
      for (int tt = 0; tt < 5; ++tt)
#pragma unroll
        for (int r = 0; r < 4; ++r) {
          int h = (w * 5 + tt) * 16 + 4 * q + r;
          outb[(long)h * 4096 + rt * 64 + half * 16 + lo] =
              (h < 300) ? f2b(acc[half][tt][r]) : (us)0;
        }
  }
}

// ---------------- K3: per-doc logits, softmax, A/fri out, G2r, combine, out ----------------
__global__ __launch_bounds__(512) void k_doc(
    const us* __restrict__ Pg, const us* __restrict__ Cg, const us* __restrict__ G2eT,
    const us* __restrict__ G1T, const us* __restrict__ G3T,
    const float* __restrict__ scG, const float* __restrict__ c2,
    const float* __restrict__ b_r, const float* __restrict__ W_cls,
    const float* __restrict__ b_cls,
    float* __restrict__ outp, float* __restrict__ outA, float* __restrict__ outF) {
  __shared__ __align__(16) float LA[64 * 68];
  __shared__ __align__(16) us AtL[64 * 72];
  __shared__ float pm[512], ps[512];
  __shared__ float friS[64], rsS[64];
  __shared__ float finP2[4 * 320];
  int d = blockIdx.x, t = threadIdx.x;
  int w = t >> 6, lane = t & 63, lo = lane & 15, q = lane >> 4;
  const f32x4 z4 = {0.f, 0.f, 0.f, 0.f};

  if (t < 64) {    // fri = softmax(scores)
    float sc = scG[d * 64 + t], m = sc;
#pragma unroll
    for (int o = 32; o > 0; o >>= 1) m = fmaxf(m, __shfl_xor(m, o));
    float e = expf(sc - m), sum = e;
#pragma unroll
    for (int o = 32; o > 0; o >>= 1) sum += __shfl_xor(sum, o);
    float f = e / sum;
    friS[t] = f;
    outF[d * 64 + t] = f;
  }

  // logits L = P @ C^T (64x64, K=320)
  {
    const us* Pd = Pg + (long)d * 64 * 320;
    const us* Cd = Cg + (long)d * 64 * 320;
    int m = w >> 1, np = (w & 1) * 2;
    f32x4 acc2[2] = { z4, z4 };
    sweepG<2>(Pd, Cd, m * 16, np, lo, q, 10, acc2);
#pragma unroll
    for (int r = 0; r < 4; ++r) {
      int row = m * 16 + 4 * q + r;
      int c0 = np * 16 + lo, c1 = c0 + 16;
      LA[row * 68 + c0] = (row == c0) ? NEG_INF : acc2[0][r];
      LA[row * 68 + c1] = (row == c1) ? NEG_INF : acc2[1][r];
    }
  }
  __syncthreads();

  // column softmax over i for each j; write A (fp32), AtL (bf16), LA=a
  {
    int j = lane;
    float mx = -3.0e38f;
#pragma unroll
    for (int ii = 0; ii < 8; ++ii) mx = fmaxf(mx, LA[(w * 8 + ii) * 68 + j]);
    pm[w * 64 + j] = mx;
    __syncthreads();
    float gm = pm[j];
#pragma unroll
    for (int k = 1; k < 8; ++k) gm = fmaxf(gm, pm[k * 64 + j]);
    float ev[8], ss = 0.f;
#pragma unroll
    for (int ii = 0; ii < 8; ++ii) {
      float e = expf(LA[(w * 8 + ii) * 68 + j] - gm);
      ev[ii] = e; ss += e;
    }
    ps[w * 64 + j] = ss;
    __syncthreads();
    float tot = ps[j];
#pragma unroll
    for (int k = 1; k < 8; ++k) tot += ps[k * 64 + j];
    float inv = 1.f / tot;
    float* Ad = outA + (long)d * 4096;
#pragma unroll
    for (int ii = 0; ii < 8; ++ii) {
      int i = w * 8 + ii;
      float a = ev[ii] * inv;
      Ad[i * 64 + j] = a;
      AtL[j * 72 + i] = f2b(a);
      LA[i * 68 + j] = a;
    }
  }
  __syncthreads();
  if (t < 64) {   // rs[i] = sum_j A[i][j]
    float s = 0.f;
    for (int jj = 0; jj < 64; ++jj) s += LA[t * 68 + jj];
    rsS[t] = s;
  }
  __syncthreads();

  // G2r = A^T @ G2e (K=64) + combine + column-reduce over sentences
  {
    int mg = w & 3, nh = w >> 2;
    f32x4 a10[10];
#pragma unroll
    for (int b = 0; b < 10; ++b) a10[b] = z4;
#pragma unroll
    for (int ks = 0; ks < 2; ++ks) {
      bf16x8 aA = ld8(AtL + (mg * 16 + lo) * 72 + 32 * ks + 8 * q);
#pragma unroll
      for (int tt = 0; tt < 10; ++tt) {
        bf16x8 bv = ld8(G2eT + (long)((nh * 10 + tt) * 16 + lo) * 4096 +
                        d * 64 + 32 * ks + 8 * q);
        a10[tt] = MFMA16(aA, bv, a10[tt], 0, 0, 0);
      }
    }
#pragma unroll
    for (int tt = 0; tt < 10; ++tt) {
      int col = (nh * 10 + tt) * 16 + lo;
      if (col < 300) {
        float bb = b_r[col], cc = c2[col];
        // transposed G1/G3: 4 consecutive rows per lane -> ushort4
        ushort4 g1v = *(const ushort4*)(G1T + (long)col * 4096 + d * 64 + mg * 16 + 4 * q);
        ushort4 g3v = *(const ushort4*)(G3T + (long)col * 4096 + d * 64 + mg * 16 + 4 * q);
        float g1a[4] = { b2f(g1v.x), b2f(g1v.y), b2f(g1v.z), b2f(g1v.w) };
        float g3a[4] = { b2f(g3v.x), b2f(g3v.y), b2f(g3v.z), b2f(g3v.w) };
        float csum = 0.f;
#pragma unroll
        for (int r = 0; r < 4; ++r) {
          int i = mg * 16 + 4 * q + r;
          csum += lrelu(a10[tt][r] + g1a[r] + rsS[i] * g3a[r] + friS[i] * cc + bb);
        }
        csum += __shfl_xor(csum, 16);
        csum += __shfl_xor(csum, 32);
        if (q == 0) finP2[mg * 320 + col] = csum;
      }
    }
  }
  __syncthreads();

  if (t < 128) {   // out = (mean_i ri) @ W_cls^T + b_cls
    int cls = t >> 6, ln = t & 63;
    float s = 0.f;
    for (int h = ln; h < 300; h += 64)
      s += (finP2[h] + finP2[320 + h] + finP2[640 + h] + finP2[960 + h]) *
           W_cls[cls * 300 + h];
#pragma unroll
    for (int o = 32; o > 0; o >>= 1) s += __shfl_xor(s, o);
    if (ln == 0) outp[d * 2 + cls] = s * 0.015625f + b_cls[cls];
  }
}

extern "C" void kernel_launch(void* const* d_in, const int* in_sizes, int n_in,
                              void* d_out, int out_size, void* d_ws, size_t ws_size,
                              hipStream_t stream) {
  const int*   wi     = (const int*)d_in[0];
  const float* E      = (const float*)d_in[1];
  const float* W_sent = (const float*)d_in[2];
  const float* b_sent = (const float*)d_in[3];
  const float* W_par  = (const float*)d_in[4];
  const float* b_par  = (const float*)d_in[5];
  const float* W_ch   = (const float*)d_in[6];
  const float* b_ch   = (const float*)d_in[7];
  const float* w_root = (const float*)d_in[8];
  const float* b_root = (const float*)d_in[9];  (void)b_root;
  const float* root_e = (const float*)d_in[10];
  const float* W_r    = (const float*)d_in[11];
  const float* b_r    = (const float*)d_in[12];
  const float* W_cls  = (const float*)d_in[13];
  const float* b_cls  = (const float*)d_in[14];

  us* B = (us*)d_ws;
  us* Wsb   = B;                      // [320][320] bf16
  us* Wpb   = B + 102400;
  us* Wcb   = B + 204800;
  us* Wr3b  = B + 307200;             // 3 x [320][320] bf16
  float* c2 = (float*)(B + 614400);   // [320] fp32
  us* encG  = B + 615040;             // [4096][320] bf16
  us* Pg    = B + 1925760;            // [4096][320] bf16
  us* Cg    = B + 3236480;            // [4096][320] bf16
  us* G1T   = B + 4547200;            // [320][4096] bf16 (transposed)
  us* G3T   = B + 5857920;            // [320][4096] bf16 (transposed)
  us* G2eT  = B + 7168640;            // [320][4096] bf16 (transposed)
  float* scG = (float*)(B + 8479360); // [4096] fp32 scores

  float* outp = (float*)d_out;        // [out(128) | A(262144) | fri(4096)]
  float* outA = outp + 128;
  float* outF = outp + 128 + 262144;

  k_prep0<<<128, 256, 0, stream>>>(W_sent, Wsb);
  k_encprep<<<288, 256, 0, stream>>>(wi, E, Wsb, b_sent, w_root,
                                     W_par, W_ch, W_r, root_e,
                                     encG, scG, Wpb, Wcb, Wr3b, c2);
  k_panels<<<dim3(64, 5), 256, 0, stream>>>(encG, Wpb, Wcb, Wr3b,
                                            b_par, b_ch, Pg, Cg, G1T, G3T, G2eT);
  k_doc<<<64, 512, 0, stream>>>(Pg, Cg, G2eT, G1T, G3T, scG, c2,
                                b_r, W_cls, b_cls, outp, outA, outF);
}

// Round 6
// 176.727 us; speedup vs baseline: 1.0043x; 1.0043x over previous
//
#include <hip/hip_runtime.h>

#define NEG_INF (-9999999.0f)

typedef __attribute__((ext_vector_type(8))) short bf16x8;
typedef __attribute__((ext_vector_type(4))) float f32x4;
typedef unsigned short us;
typedef unsigned int u32;

#define MFMA16 __builtin_amdgcn_mfma_f32_16x16x32_bf16

__device__ __forceinline__ float b2f(us u) {
  union { unsigned int i; float f; } x; x.i = ((unsigned int)u) << 16; return x.f;
}
__device__ __forceinline__ us f2b(float f) {
  union { float f; unsigned int i; } x; x.f = f;
  unsigned int r = x.i + 0x7fffu + ((x.i >> 16) & 1u);
  return (us)(r >> 16);
}
__device__ __forceinline__ float lrelu(float v) { return v > 0.f ? v : 0.01f * v; }
__device__ __forceinline__ bf16x8 ld8(const us* p) { return *reinterpret_cast<const bf16x8*>(p); }
// XOR swizzle for N-row x 320-col bf16 LDS panels (row pitch 640 B).
__device__ __forceinline__ int swz(int row) { return (row & 7) << 4; }

// ---------------- prep0: Ws -> bf16 [320][320] (critical path only) ----------------
__global__ __launch_bounds__(256) void k_prep0(
    const float* __restrict__ Ws, us* __restrict__ Wsb) {
  int gid = blockIdx.x * 256 + threadIdx.x;
  for (int i = gid; i < 320 * 320; i += 128 * 256) {
    int r = i / 320, c = i - r * 320;
    Wsb[i] = (r < 300 && c < 300) ? f2b(Ws[r * 300 + c]) : (us)0;
  }
}

// ------- sweepM: M A-row-tiles from swizzled LDS, B rows from global (depth-2) --
template<int M, int NT, int KS>
__device__ __forceinline__ void sweepM(const us* __restrict__ Alds, const int (&rr)[M],
    int q, int lo, const us* __restrict__ Bg, int n0, f32x4 (&acc)[M][NT]) {
  const char* ab = (const char*)Alds;
  int ao[M], sw[M];
#pragma unroll
  for (int m = 0; m < M; ++m) { ao[m] = rr[m] * 640; sw[m] = swz(rr[m]); }
  const us* br[NT];
#pragma unroll
  for (int t = 0; t < NT; ++t)
    br[t] = Bg + (long)((n0 + t) * 16 + lo) * 320 + 8 * q;
  bf16x8 aC[M], aN[M], b0[NT], b1[NT];
#pragma unroll
  for (int m = 0; m < M; ++m) {
    aC[m] = *(const bf16x8*)(ab + ao[m] + ((16 * q) ^ sw[m]));
    aN[m] = *(const bf16x8*)(ab + ao[m] + ((64 + 16 * q) ^ sw[m]));
  }
#pragma unroll
  for (int t = 0; t < NT; ++t) b0[t] = ld8(br[t]);
#pragma unroll
  for (int t = 0; t < NT; ++t) b1[t] = ld8(br[t] + 32);
#pragma unroll
  for (int ks = 0; ks < KS - 2; ++ks) {
    bf16x8 aF[M], bF[NT];
    const int kb = 64 * (ks + 2) + 16 * q;
#pragma unroll
    for (int m = 0; m < M; ++m) aF[m] = *(const bf16x8*)(ab + ao[m] + (kb ^ sw[m]));
#pragma unroll
    for (int t = 0; t < NT; ++t) bF[t] = ld8(br[t] + (ks + 2) * 32);
#pragma unroll
    for (int t = 0; t < NT; ++t)
#pragma unroll
      for (int m = 0; m < M; ++m)
        acc[m][t] = MFMA16(aC[m], b0[t], acc[m][t], 0, 0, 0);
#pragma unroll
    for (int m = 0; m < M; ++m) { aC[m] = aN[m]; aN[m] = aF[m]; }
#pragma unroll
    for (int t = 0; t < NT; ++t) { b0[t] = b1[t]; b1[t] = bF[t]; }
  }
#pragma unroll
  for (int t = 0; t < NT; ++t)
#pragma unroll
    for (int m = 0; m < M; ++m) acc[m][t] = MFMA16(aC[m], b0[t], acc[m][t], 0, 0, 0);
#pragma unroll
  for (int t = 0; t < NT; ++t)
#pragma unroll
    for (int m = 0; m < M; ++m) acc[m][t] = MFMA16(aN[m], b1[t], acc[m][t], 0, 0, 0);
}

// ------- sweepT: A (output h-rows) from global weight rows, B = NB x 16 enc rows (LDS) ----
template<int NB, int NT, int KS>
__device__ __forceinline__ void sweepT(const us* __restrict__ es, int q, int lo,
    const us* __restrict__ Ag, int n0, f32x4 (&acc)[NB][NT]) {
  const char* eb = (const char*)es;
  int bo[NB], sb[NB];
#pragma unroll
  for (int h = 0; h < NB; ++h) { bo[h] = (lo + 16 * h) * 640; sb[h] = swz(lo + 16 * h); }
  const us* ar[NT];
#pragma unroll
  for (int t = 0; t < NT; ++t)
    ar[t] = Ag + (long)((n0 + t) * 16 + lo) * 320 + 8 * q;
  bf16x8 a0[NT], a1[NT], bC[NB], bN[NB];
#pragma unroll
  for (int t = 0; t < NT; ++t) a0[t] = ld8(ar[t]);
#pragma unroll
  for (int h = 0; h < NB; ++h)
    bC[h] = *(const bf16x8*)(eb + bo[h] + ((16 * q) ^ sb[h]));
#pragma unroll
  for (int t = 0; t < NT; ++t) a1[t] = ld8(ar[t] + 32);
#pragma unroll
  for (int h = 0; h < NB; ++h)
    bN[h] = *(const bf16x8*)(eb + bo[h] + ((64 + 16 * q) ^ sb[h]));
#pragma unroll
  for (int ks = 0; ks < KS - 2; ++ks) {
    bf16x8 a2[NT], bF[NB];
    const int kb = 64 * (ks + 2) + 16 * q;
#pragma unroll
    for (int t = 0; t < NT; ++t) a2[t] = ld8(ar[t] + (ks + 2) * 32);
#pragma unroll
    for (int h = 0; h < NB; ++h)
      bF[h] = *(const bf16x8*)(eb + bo[h] + (kb ^ sb[h]));
#pragma unroll
    for (int t = 0; t < NT; ++t)
#pragma unroll
      for (int h = 0; h < NB; ++h)
        acc[h][t] = MFMA16(a0[t], bC[h], acc[h][t], 0, 0, 0);
#pragma unroll
    for (int t = 0; t < NT; ++t) { a0[t] = a1[t]; a1[t] = a2[t]; }
#pragma unroll
    for (int h = 0; h < NB; ++h) { bC[h] = bN[h]; bN[h] = bF[h]; }
  }
#pragma unroll
  for (int t = 0; t < NT; ++t)
#pragma unroll
    for (int h = 0; h < NB; ++h) acc[h][t] = MFMA16(a0[t], bC[h], acc[h][t], 0, 0, 0);
#pragma unroll
  for (int t = 0; t < NT; ++t)
#pragma unroll
    for (int h = 0; h < NB; ++h) acc[h][t] = MFMA16(a1[t], bN[h], acc[h][t], 0, 0, 0);
}

// ------- sweepG: both operands from global (depth-2) — for k_doc logits ----------
template<int NT>
__device__ __forceinline__ void sweepG(const us* __restrict__ Ab,
    const us* __restrict__ Bb, int m0, int nt0, int lo, int q, int ksn, f32x4* acc) {
  const us* ar = Ab + (long)(m0 + lo) * 320 + 8 * q;
  const us* br[NT];
#pragma unroll
  for (int t = 0; t < NT; ++t)
    br[t] = Bb + (long)((nt0 + t) * 16 + lo) * 320 + 8 * q;
  bf16x8 a0 = ld8(ar), a1 = ld8(ar + 32);
  bf16x8 b0[NT], b1[NT];
#pragma unroll
  for (int t = 0; t < NT; ++t) b0[t] = ld8(br[t]);
#pragma unroll
  for (int t = 0; t < NT; ++t) b1[t] = ld8(br[t] + 32);
  for (int ks = 0; ks < ksn - 2; ++ks) {
    bf16x8 a2 = ld8(ar + (ks + 2) * 32);
    bf16x8 b2[NT];
#pragma unroll
    for (int t = 0; t < NT; ++t) b2[t] = ld8(br[t] + (ks + 2) * 32);
#pragma unroll
    for (int t = 0; t < NT; ++t)
      acc[t] = MFMA16(a0, b0[t], acc[t], 0, 0, 0);
    a0 = a1; a1 = a2;
#pragma unroll
    for (int t = 0; t < NT; ++t) { b0[t] = b1[t]; b1[t] = b2[t]; }
  }
#pragma unroll
  for (int t = 0; t < NT; ++t)
    acc[t] = MFMA16(a0, b0[t], acc[t], 0, 0, 0);
#pragma unroll
  for (int t = 0; t < NT; ++t)
    acc[t] = MFMA16(a1, b1[t], acc[t], 0, 0, 0);
}

// ------- K1: x<128: gather + enc(M=2) + scores; x>=128: convert Wp/Wc/Wr3/c2 ---------
__global__ __launch_bounds__(256) void k_encprep(
    const int* __restrict__ wi, const float* __restrict__ E,
    const us* __restrict__ Wsb, const float* __restrict__ b_sent,
    const float* __restrict__ w_root,
    const float* __restrict__ Wp, const float* __restrict__ Wc,
    const float* __restrict__ Wr, const float* __restrict__ root,
    us* __restrict__ encG, float* __restrict__ scG,
    us* __restrict__ Wpb, us* __restrict__ Wcb, us* __restrict__ Wr3b,
    float* __restrict__ c2) {
  int t = threadIdx.x;
  if (blockIdx.x >= 128) {
    int gid = (blockIdx.x - 128) * 256 + t;
    const int stride = 160 * 256;
    for (int i = gid; i < 5 * 102400; i += stride) {
      int p = i / 102400, rem = i - p * 102400;
      int r = rem / 320, c = rem - r * 320;
      us v = 0;
      if (r < 300 && c < 300) {
        if (p == 0)      v = f2b(Wp[r * 300 + c]);
        else if (p == 1) v = f2b(Wc[r * 300 + c]);
        else             v = f2b(Wr[r * 900 + (p - 2) * 300 + c]);
      }
      if (p == 0)      Wpb[rem] = v;
      else if (p == 1) Wcb[rem] = v;
      else             Wr3b[(p - 2) * 102400 + rem] = v;
    }
    if (gid < 2560) {   // c2[c] = sum_h Wr2[c][h]*root[h]
      int c = gid >> 3, p = gid & 7;
      float s = 0.f;
      if (c < 300)
        for (int h = p; h < 300; h += 8) s = fmaf(Wr[c * 900 + 300 + h], root[h], s);
      s += __shfl_xor(s, 1); s += __shfl_xor(s, 2); s += __shfl_xor(s, 4);
      if (p == 0) c2[c] = s;
    }
    return;
  }
  // ---- enc path: 32-row tile ----
  __shared__ __align__(16) us xs[32 * 320];
  __shared__ __align__(16) us es[32 * 320];
  int r0g = blockIdx.x * 32;
  {
    int row = t >> 3, p = t & 7;
    int widx = wi[((r0g + row) << 6) + 63];
    const float4* er = (const float4*)(E + (long)widx * 300);
    char* rowb = (char*)xs + row * 640;
    int sw = swz(row);
    for (int j = p; j < 75; j += 8) {
      float4 v = er[j];
      *(ushort4*)(rowb + ((8 * j) ^ sw)) =
          make_ushort4(f2b(v.x), f2b(v.y), f2b(v.z), f2b(v.w));
    }
    for (int c = 300 + p; c < 320; c += 8)    // zero K-pad cols
      *(us*)(rowb + ((2 * c) ^ sw)) = 0;
  }
  __syncthreads();
  int w = t >> 6, lane = t & 63, lo = lane & 15, q = lane >> 4;
  const f32x4 z4 = {0.f, 0.f, 0.f, 0.f};
  int rr[2] = { lo, 16 + lo };
  f32x4 acc[2][5];
#pragma unroll
  for (int a = 0; a < 2; ++a)
#pragma unroll
    for (int b = 0; b < 5; ++b) acc[a][b] = z4;
  sweepM<2, 5, 10>(xs, rr, q, lo, Wsb, w * 5, acc);
#pragma unroll
  for (int m = 0; m < 2; ++m)
#pragma unroll
    for (int tt = 0; tt < 5; ++tt) {
      int col = (w * 5 + tt) * 16 + lo;
      float bb = (col < 300) ? b_sent[col] : 0.f;
#pragma unroll
      for (int r = 0; r < 4; ++r) {
        int row = m * 16 + 4 * q + r;
        us hv = (col < 300) ? f2b(lrelu(acc[m][tt][r] + bb)) : (us)0;
        *(us*)((char*)es + row * 640 + ((2 * col) ^ swz(row))) = hv;
        encG[(long)(r0g + row) * 320 + col] = hv;
      }
    }
  __syncthreads();
  // scores = enc @ w_root (b_root omitted: softmax-invariant)
  {
    int row = t >> 3, p = t & 7;
    float s = 0.f;
    for (int cch = p; cch < 38; cch += 8) {
      bf16x8 v = *(const bf16x8*)((const char*)es + row * 640 + ((16 * cch) ^ swz(row)));
#pragma unroll
      for (int e = 0; e < 8; ++e) {
        int h = cch * 8 + e;
        if (h < 300) s = fmaf(b2f((us)v[e]), w_root[h], s);
      }
    }
    s += __shfl_xor(s, 1); s += __shfl_xor(s, 2); s += __shfl_xor(s, 4);
    if (p == 0) scG[r0g + row] = s;
  }
}

// ---------------- K2: 128 row-tiles (32 rows) x 5 tasks {P, C, G1T, G3T, G2eT} ------------
__global__ __launch_bounds__(256) void k_panels(
    const us* __restrict__ encG,
    const us* __restrict__ Wpb, const us* __restrict__ Wcb, const us* __restrict__ Wrb,
    const float* __restrict__ b_par, const float* __restrict__ b_ch,
    us* __restrict__ Pg, us* __restrict__ Cg, us* __restrict__ G1T, us* __restrict__ G3T,
    us* __restrict__ G2eT) {
  __shared__ __align__(16) us es[32 * 320];
  int t = threadIdx.x, task = blockIdx.y, rt = blockIdx.x;
  // stage 32-row enc tile (pad cols already zero in encG), swizzled
  {
    const float4* src = (const float4*)(encG + (long)rt * 32 * 320);
    for (int i = t; i < 1280; i += 256) {
      int row = i / 40, c16 = i - row * 40;
      float4 v = src[i];
      *(float4*)((char*)es + row * 640 + ((c16 * 16) ^ swz(row))) = v;
    }
  }
  __syncthreads();
  int w = t >> 6, lane = t & 63, lo = lane & 15, q = lane >> 4;
  const f32x4 z4 = {0.f, 0.f, 0.f, 0.f};
  if (task < 2) {
    const us* Bg = task ? Wcb : Wpb;
    const float* bias = task ? b_ch : b_par;
    us* outb = task ? Cg : Pg;
    int rr[2] = { lo, 16 + lo };
    f32x4 acc[2][5];
#pragma unroll
    for (int a = 0; a < 2; ++a)
#pragma unroll
      for (int b = 0; b < 5; ++b) acc[a][b] = z4;
    sweepM<2, 5, 10>(es, rr, q, lo, Bg, w * 5, acc);
#pragma unroll
    for (int m = 0; m < 2; ++m)
#pragma unroll
      for (int tt = 0; tt < 5; ++tt) {
        int col = (w * 5 + tt) * 16 + lo;
        float bb = (col < 300) ? bias[col] : 0.f;
#pragma unroll
        for (int r = 0; r < 4; ++r) {
          int row = rt * 32 + m * 16 + 4 * q + r;
          outb[(long)row * 320 + col] =
              (col < 300) ? f2b(lrelu(acc[m][tt][r] + bb)) : (us)0;
        }
      }
  } else {
    // transposed outputs [h][row]: G1T / G3T / G2eT
    const us* Ag = (task == 2) ? Wrb : (task == 3) ? Wrb + 204800 : Wrb + 102400;
    us* outb = (task == 2) ? G1T : (task == 3) ? G3T : G2eT;
    f32x4 acc[2][5];
#pragma unroll
    for (int a = 0; a < 2; ++a)
#pragma unroll
      for (int b = 0; b < 5; ++b) acc[a][b] = z4;
    sweepT<2, 5, 10>(es, q, lo, Ag, w * 5, acc);
#pragma unroll
    for (int half = 0; half < 2; ++half)
#pragma unroll
      for (int tt = 0; tt < 5; ++tt)
#pragma unroll
        for (int r = 0; r < 4; ++r) {
          int h = (w * 5 + tt) * 16 + 4 * q + r;
          outb[(long)h * 4096 + rt * 32 + half * 16 + lo] =
              (h < 300) ? f2b(acc[half][tt][r]) : (us)0;
        }
  }
}

// -------- K3: per-doc logits, softmax, A/fri out, G2r, combine, out (16 waves) ------------
__global__ __launch_bounds__(1024) void k_doc(
    const us* __restrict__ Pg, const us* __restrict__ Cg, const us* __restrict__ G2eT,
    const us* __restrict__ G1T, const us* __restrict__ G3T,
    const float* __restrict__ scG, const float* __restrict__ c2,
    const float* __restrict__ b_r, const float* __restrict__ W_cls,
    const float* __restrict__ b_cls,
    float* __restrict__ outp, float* __restrict__ outA, float* __restrict__ outF) {
  __shared__ __align__(16) float LA[64 * 68];
  __shared__ __align__(16) us AtL[64 * 72];
  __shared__ float pm[16 * 64], ps[16 * 64];
  __shared__ float friS[64], rsS[64];
  __shared__ float finP2[4 * 320];
  int d = blockIdx.x, t = threadIdx.x;
  int w = t >> 6, lane = t & 63, lo = lane & 15, q = lane >> 4;
  const f32x4 z4 = {0.f, 0.f, 0.f, 0.f};

  if (t < 64) {    // fri = softmax(scores)
    float sc = scG[d * 64 + t], m = sc;
#pragma unroll
    for (int o = 32; o > 0; o >>= 1) m = fmaxf(m, __shfl_xor(m, o));
    float e = expf(sc - m), sum = e;
#pragma unroll
    for (int o = 32; o > 0; o >>= 1) sum += __shfl_xor(sum, o);
    float f = e / sum;
    friS[t] = f;
    outF[d * 64 + t] = f;
  }

  // logits L = P @ C^T (64x64, K=320): 16 waves, 1 16x16 tile each
  {
    const us* Pd = Pg + (long)d * 64 * 320;
    const us* Cd = Cg + (long)d * 64 * 320;
    int m = w >> 2, np = w & 3;
    f32x4 acc1[1] = { z4 };
    sweepG<1>(Pd, Cd, m * 16, np, lo, q, 10, acc1);
#pragma unroll
    for (int r = 0; r < 4; ++r) {
      int row = m * 16 + 4 * q + r;
      int c0 = np * 16 + lo;
      LA[row * 68 + c0] = (row == c0) ? NEG_INF : acc1[0][r];
    }
  }
  __syncthreads();

  // column softmax over i for each j (4 rows per wave); write A, AtL, LA=a
  {
    int j = lane;
    float mx = -3.0e38f;
#pragma unroll
    for (int ii = 0; ii < 4; ++ii) mx = fmaxf(mx, LA[(w * 4 + ii) * 68 + j]);
    pm[w * 64 + j] = mx;
    __syncthreads();
    float gm = pm[j];
#pragma unroll
    for (int k = 1; k < 16; ++k) gm = fmaxf(gm, pm[k * 64 + j]);
    float ev[4], ss = 0.f;
#pragma unroll
    for (int ii = 0; ii < 4; ++ii) {
      float e = expf(LA[(w * 4 + ii) * 68 + j] - gm);
      ev[ii] = e; ss += e;
    }
    ps[w * 64 + j] = ss;
    __syncthreads();
    float tot = ps[j];
#pragma unroll
    for (int k = 1; k < 16; ++k) tot += ps[k * 64 + j];
    float inv = 1.f / tot;
    float* Ad = outA + (long)d * 4096;
#pragma unroll
    for (int ii = 0; ii < 4; ++ii) {
      int i = w * 4 + ii;
      float a = ev[ii] * inv;
      Ad[i * 64 + j] = a;
      AtL[j * 72 + i] = f2b(a);
      LA[i * 68 + j] = a;
    }
  }
  __syncthreads();
  {   // rs[i] = sum_j A[i][j], 16 lanes per row
    int i = t >> 4, p = t & 15;
    if (i < 64) {
      float s = 0.f;
#pragma unroll
      for (int jj = p; jj < 64; jj += 16) s += LA[i * 68 + jj];
      s += __shfl_xor(s, 1); s += __shfl_xor(s, 2);
      s += __shfl_xor(s, 4); s += __shfl_xor(s, 8);
      if (p == 0) rsS[i] = s;
    }
  }
  __syncthreads();

  // G2r = A^T @ G2e (K=64) + combine + column-reduce: 16 waves = 4 mg x 4 nh
  {
    int mg = w & 3, nh = w >> 2;
    f32x4 a5[5];
#pragma unroll
    for (int b = 0; b < 5; ++b) a5[b] = z4;
#pragma unroll
    for (int ks = 0; ks < 2; ++ks) {
      bf16x8 aA = ld8(AtL + (mg * 16 + lo) * 72 + 32 * ks + 8 * q);
#pragma unroll
      for (int tt = 0; tt < 5; ++tt) {
        bf16x8 bv = ld8(G2eT + (long)((nh * 5 + tt) * 16 + lo) * 4096 +
                        d * 64 + 32 * ks + 8 * q);
        a5[tt] = MFMA16(aA, bv, a5[tt], 0, 0, 0);
      }
    }
#pragma unroll
    for (int tt = 0; tt < 5; ++tt) {
      int col = (nh * 5 + tt) * 16 + lo;
      if (col < 300) {
        float bb = b_r[col], cc = c2[col];
        ushort4 g1v = *(const ushort4*)(G1T + (long)col * 4096 + d * 64 + mg * 16 + 4 * q);
        ushort4 g3v = *(const ushort4*)(G3T + (long)col * 4096 + d * 64 + mg * 16 + 4 * q);
        float g1a[4] = { b2f(g1v.x), b2f(g1v.y), b2f(g1v.z), b2f(g1v.w) };
        float g3a[4] = { b2f(g3v.x), b2f(g3v.y), b2f(g3v.z), b2f(g3v.w) };
        float csum = 0.f;
#pragma unroll
        for (int r = 0; r < 4; ++r) {
          int i = mg * 16 + 4 * q + r;
          csum += lrelu(a5[tt][r] + g1a[r] + rsS[i] * g3a[r] + friS[i] * cc + bb);
        }
        csum += __shfl_xor(csum, 16);
        csum += __shfl_xor(csum, 32);
        if (q == 0) finP2[mg * 320 + col] = csum;
      }
    }
  }
  __syncthreads();

  if (t < 128) {   // out = (mean_i ri) @ W_cls^T + b_cls
    int cls = t >> 6, ln = t & 63;
    float s = 0.f;
    for (int h = ln; h < 300; h += 64)
      s += (finP2[h] + finP2[320 + h] + finP2[640 + h] + finP2[960 + h]) *
           W_cls[cls * 300 + h];
#pragma unroll
    for (int o = 32; o > 0; o >>= 1) s += __shfl_xor(s, o);
    if (ln == 0) outp[d * 2 + cls] = s * 0.015625f + b_cls[cls];
  }
}

extern "C" void kernel_launch(void* const* d_in, const int* in_sizes, int n_in,
                              void* d_out, int out_size, void* d_ws, size_t ws_size,
                              hipStream_t stream) {
  const int*   wi     = (const int*)d_in[0];
  const float* E      = (const float*)d_in[1];
  const float* W_sent = (const float*)d_in[2];
  const float* b_sent = (const float*)d_in[3];
  const float* W_par  = (const float*)d_in[4];
  const float* b_par  = (const float*)d_in[5];
  const float* W_ch   = (const float*)d_in[6];
  const float* b_ch   = (const float*)d_in[7];
  const float* w_root = (const float*)d_in[8];
  const float* b_root = (const float*)d_in[9];  (void)b_root;
  const float* root_e = (const float*)d_in[10];
  const float* W_r    = (const float*)d_in[11];
  const float* b_r    = (const float*)d_in[12];
  const float* W_cls  = (const float*)d_in[13];
  const float* b_cls  = (const float*)d_in[14];

  us* B = (us*)d_ws;
  us* Wsb   = B;                      // [320][320] bf16
  us* Wpb   = B + 102400;
  us* Wcb   = B + 204800;
  us* Wr3b  = B + 307200;             // 3 x [320][320] bf16
  float* c2 = (float*)(B + 614400);   // [320] fp32
  us* encG  = B + 615040;             // [4096][320] bf16
  us* Pg    = B + 1925760;            // [4096][320] bf16
  us* Cg    = B + 3236480;            // [4096][320] bf16
  us* G1T   = B + 4547200;            // [320][4096] bf16 (transposed)
  us* G3T   = B + 5857920;            // [320][4096] bf16 (transposed)
  us* G2eT  = B + 7168640;            // [320][4096] bf16 (transposed)
  float* scG = (float*)(B + 8479360); // [4096] fp32 scores

  float* outp = (float*)d_out;        // [out(128) | A(262144) | fri(4096)]
  float* outA = outp + 128;
  float* outF = outp + 128 + 262144;

  k_prep0<<<128, 256, 0, stream>>>(W_sent, Wsb);
  k_encprep<<<288, 256, 0, stream>>>(wi, E, Wsb, b_sent, w_root,
                                     W_par, W_ch, W_r, root_e,
                                     encG, scG, Wpb, Wcb, Wr3b, c2);
  k_panels<<<dim3(128, 5), 256, 0, stream>>>(encG, Wpb, Wcb, Wr3b,
                                             b_par, b_ch, Pg, Cg, G1T, G3T, G2eT);
  k_doc<<<64, 1024, 0, stream>>>(Pg, Cg, G2eT, G1T, G3T, scG, c2,
                                 b_r, W_cls, b_cls, outp, outA, outF);
}